// Round 6
// baseline (213.068 us; speedup 1.0000x reference)
//
#include <hip/hip_runtime.h>
#include <cstddef>

#define NB 8
#define NT 2048
#define NE 256
#define NH 4
#define ND 64
#define NP 8

typedef short bf16x8 __attribute__((ext_vector_type(8)));
typedef float f32x4 __attribute__((ext_vector_type(4)));

__device__ __forceinline__ unsigned short f2bf(float f) {
  unsigned u = __builtin_bit_cast(unsigned, f);
  u += 0x7fffu + ((u >> 16) & 1u);          // RNE
  return (unsigned short)(u >> 16);
}
__device__ __forceinline__ float bf2f(unsigned short h) {
  unsigned u = ((unsigned)h) << 16;
  return __builtin_bit_cast(float, u);
}
// packed hi/lo split of a float pair (integer-only, no HIP vector types)
__device__ __forceinline__ void split2(float a, float b, unsigned& hi, unsigned& lo) {
  const unsigned short ha = f2bf(a), hb = f2bf(b);
  hi = (unsigned)ha | ((unsigned)hb << 16);
  const unsigned short la = f2bf(a - bf2f(ha));
  const unsigned short lb = f2bf(b - bf2f(hb));
  lo = (unsigned)la | ((unsigned)lb << 16);
}
__device__ __forceinline__ void gld16(const void* g, void* l) {
  __builtin_amdgcn_global_load_lds((const __attribute__((address_space(1))) unsigned*)g,
                                   (__attribute__((address_space(3))) unsigned*)l, 16, 0, 0);
}

// ---------------- setup: wqk split(+q prescale), w_in split, prep(uv->wqkv rows), zero --
// grid 578: [0,512) wqk, [512,576) w_in, 576 prep, 577 psum-zero
__global__ __launch_bounds__(256) void setup_kernel(
    const float* __restrict__ w_in, const float* __restrict__ w_q,
    const float* __restrict__ w_k, const float* __restrict__ b_q,
    const float* __restrict__ b_k, const float* __restrict__ w_o,
    const float* __restrict__ b_o, const float* __restrict__ w_bd,
    const float* __restrict__ b_bd, const float* __restrict__ w_v,
    const float* __restrict__ b_v,
    unsigned short* __restrict__ wihi, unsigned short* __restrict__ wilo,
    unsigned short* __restrict__ wqkvhi, unsigned short* __restrict__ wqkvlo,
    float* __restrict__ bqk, float* __restrict__ consts, float* __restrict__ psum)
{
  __shared__ float wbd_s[NE];
  __shared__ float u_s[NE];
  const int b = blockIdx.x, tid = threadIdx.x;
  if (b < 512) {
    const int i = b * 256 + tid;                         // [0,131072)
    const float v = (i < 65536) ? w_q[i] * 0.125f : w_k[i - 65536];
    const unsigned short h = f2bf(v);
    wqkvhi[i] = h;
    wqkvlo[i] = f2bf(v - bf2f(h));
    if (i < 512) bqk[i] = (i < 256) ? b_q[i] * 0.125f : b_k[i - 256];
  } else if (b < 576) {
    const int i = (b - 512) * 256 + tid;                 // float4 idx [0,16384)
    const float4 v = *(const float4*)(w_in + (size_t)i * 4);
    const float vv[4] = {v.x, v.y, v.z, v.w};
    unsigned short h4[4], l4[4];
    #pragma unroll
    for (int j = 0; j < 4; ++j) {
      h4[j] = f2bf(vv[j]);
      l4[j] = f2bf(vv[j] - bf2f(h4[j]));
    }
    *(ushort2*)(wihi + (size_t)i * 4)     = make_ushort2(h4[0], h4[1]);
    *(ushort2*)(wihi + (size_t)i * 4 + 2) = make_ushort2(h4[2], h4[3]);
    *(ushort2*)(wilo + (size_t)i * 4)     = make_ushort2(l4[0], l4[1]);
    *(ushort2*)(wilo + (size_t)i * 4 + 2) = make_ushort2(l4[2], l4[3]);
  } else if (b == 576) {
    wbd_s[tid] = w_bd[tid];
    __syncthreads();
    float a = 0.f;
    for (int j = 0; j < NE; ++j) a = fmaf(wbd_s[j], w_o[j * NE + tid], a);
    u_s[tid] = a;
    __syncthreads();
    #pragma unroll
    for (int hh = 0; hh < NH; ++hh) {
      float a2 = 0.f;
      for (int d = 0; d < ND; ++d)
        a2 = fmaf(u_s[hh * ND + d], w_v[(size_t)(hh * ND + d) * NE + tid], a2);
      const unsigned short hb = f2bf(a2);
      wqkvhi[(512 + hh) * 256 + tid] = hb;
      wqkvlo[(512 + hh) * 256 + tid] = f2bf(a2 - bf2f(hb));
    }
    for (int i = tid; i < 60 * 256; i += 256) {          // zero-pad rows 516..575
      wqkvhi[516 * 256 + i] = 0;
      wqkvlo[516 * 256 + i] = 0;
    }
    if (tid == 0) {
      float cc = 0.f;
      for (int j = 0; j < NE; ++j) cc = fmaf(wbd_s[j], b_o[j], cc);
      consts[0] = cc + b_bd[0];
    }
    if (tid < 4) {
      float cv = 0.f;
      for (int d = 0; d < ND; ++d) cv = fmaf(u_s[tid * ND + d], b_v[tid * ND + d], cv);
      bqk[512 + tid] = cv;
    } else if (tid < 64) {
      bqk[512 + tid] = 0.f;
    }
  } else {
    for (int i = tid; i < NB * NP * NE; i += 256) psum[i] = 0.f;
  }
}

// ---------------- hgemm: h = x @ w_in^T + b_in, f32 A converted in-regs ----------------
// grid (4 n-tiles, 128 m-tiles); block 256 thr = 4 waves; wave = 32 rows x 64 cols.
__global__ __launch_bounds__(256) void hgemm_kernel(
    const float* __restrict__ x,
    const unsigned short* __restrict__ wihi, const unsigned short* __restrict__ wilo,
    const float* __restrict__ b_in,
    unsigned short* __restrict__ hhi, unsigned short* __restrict__ hlo)
{
  const int tid = threadIdx.x;
  const int wave = tid >> 6, lane = tid & 63;
  const int lr = lane & 15, lg = lane >> 4;
  const int n0 = blockIdx.x * 64, m0 = blockIdx.y * 128;
  const int wrow0 = m0 + wave * 32;
  f32x4 acc[2][4];
  #pragma unroll
  for (int s = 0; s < 2; ++s)
    #pragma unroll
    for (int ns = 0; ns < 4; ++ns) acc[s][ns] = (f32x4){0.f, 0.f, 0.f, 0.f};

  #pragma unroll 2
  for (int k0 = 0; k0 < 256; k0 += 32) {
    bf16x8 ahi[2], alo[2], bf[4][2];
    #pragma unroll
    for (int s = 0; s < 2; ++s) {
      const float* xp = x + (size_t)(wrow0 + s * 16 + lr) * 256 + k0 + lg * 8;
      const float4 v0 = *(const float4*)xp;
      const float4 v1 = *(const float4*)(xp + 4);
      unsigned h0, h1, h2, h3, l0, l1, l2, l3;
      split2(v0.x, v0.y, h0, l0);
      split2(v0.z, v0.w, h1, l1);
      split2(v1.x, v1.y, h2, l2);
      split2(v1.z, v1.w, h3, l3);
      const uint4 hu = make_uint4(h0, h1, h2, h3);
      const uint4 lu = make_uint4(l0, l1, l2, l3);
      ahi[s] = __builtin_bit_cast(bf16x8, hu);
      alo[s] = __builtin_bit_cast(bf16x8, lu);
    }
    #pragma unroll
    for (int ns = 0; ns < 4; ++ns) {
      const size_t off = (size_t)(n0 + ns * 16 + lr) * 256 + k0 + lg * 8;
      bf[ns][0] = *(const bf16x8*)(wihi + off);
      bf[ns][1] = *(const bf16x8*)(wilo + off);
    }
    #pragma unroll
    for (int s = 0; s < 2; ++s)
      #pragma unroll
      for (int ns = 0; ns < 4; ++ns) {
        acc[s][ns] = __builtin_amdgcn_mfma_f32_16x16x32_bf16(ahi[s], bf[ns][0], acc[s][ns], 0, 0, 0);
        acc[s][ns] = __builtin_amdgcn_mfma_f32_16x16x32_bf16(ahi[s], bf[ns][1], acc[s][ns], 0, 0, 0);
        acc[s][ns] = __builtin_amdgcn_mfma_f32_16x16x32_bf16(alo[s], bf[ns][0], acc[s][ns], 0, 0, 0);
      }
  }
  #pragma unroll
  for (int s = 0; s < 2; ++s)
    #pragma unroll
    for (int ns = 0; ns < 4; ++ns)
      #pragma unroll
      for (int reg = 0; reg < 4; ++reg) {
        const int row = wrow0 + s * 16 + lg * 4 + reg;
        const int col = n0 + ns * 16 + lr;
        const float v = acc[s][ns][reg] + b_in[col];
        const size_t idx = (size_t)row * 256 + col;
        const unsigned short hb = f2bf(v);
        hhi[idx] = hb;
        hlo[idx] = f2bf(v - bf2f(hb));
      }
}

// ---------------- qkv-gemm: [q*0.125 | k | vu] = h @ wqkv^T + bqk ----------------------
// grid (9 n-tiles, 128 m-tiles). cols 0..255 q, 256..511 k, 512..515 vu.
__global__ __launch_bounds__(256) void qkvgemm_kernel(
    const unsigned short* __restrict__ Ahi, const unsigned short* __restrict__ Alo,
    const unsigned short* __restrict__ Whi, const unsigned short* __restrict__ Wlo,
    const float* __restrict__ bias,
    unsigned short* __restrict__ Qhi, unsigned short* __restrict__ Qlo,
    unsigned short* __restrict__ Khi, unsigned short* __restrict__ Klo,
    float* __restrict__ vubuf)
{
  const int tid = threadIdx.x;
  const int wave = tid >> 6, lane = tid & 63;
  const int lr = lane & 15, lg = lane >> 4;
  const int n0 = blockIdx.x * 64, m0 = blockIdx.y * 128;
  const int wrow0 = m0 + wave * 32;
  f32x4 acc[2][4];
  #pragma unroll
  for (int s = 0; s < 2; ++s)
    #pragma unroll
    for (int ns = 0; ns < 4; ++ns) acc[s][ns] = (f32x4){0.f, 0.f, 0.f, 0.f};

  #pragma unroll 2
  for (int k0 = 0; k0 < 256; k0 += 32) {
    bf16x8 a[2][2], bf[4][2];
    #pragma unroll
    for (int s = 0; s < 2; ++s) {
      const size_t off = (size_t)(wrow0 + s * 16 + lr) * 256 + k0 + lg * 8;
      a[s][0] = *(const bf16x8*)(Ahi + off);
      a[s][1] = *(const bf16x8*)(Alo + off);
    }
    #pragma unroll
    for (int ns = 0; ns < 4; ++ns) {
      const size_t off = (size_t)(n0 + ns * 16 + lr) * 256 + k0 + lg * 8;
      bf[ns][0] = *(const bf16x8*)(Whi + off);
      bf[ns][1] = *(const bf16x8*)(Wlo + off);
    }
    #pragma unroll
    for (int s = 0; s < 2; ++s)
      #pragma unroll
      for (int ns = 0; ns < 4; ++ns) {
        acc[s][ns] = __builtin_amdgcn_mfma_f32_16x16x32_bf16(a[s][0], bf[ns][0], acc[s][ns], 0, 0, 0);
        acc[s][ns] = __builtin_amdgcn_mfma_f32_16x16x32_bf16(a[s][0], bf[ns][1], acc[s][ns], 0, 0, 0);
        acc[s][ns] = __builtin_amdgcn_mfma_f32_16x16x32_bf16(a[s][1], bf[ns][0], acc[s][ns], 0, 0, 0);
      }
  }
  #pragma unroll
  for (int s = 0; s < 2; ++s)
    #pragma unroll
    for (int ns = 0; ns < 4; ++ns)
      #pragma unroll
      for (int reg = 0; reg < 4; ++reg) {
        const int row = wrow0 + s * 16 + lg * 4 + reg;
        const int col = n0 + ns * 16 + lr;
        const float v = acc[s][ns][reg] + bias[col];
        const int b = row >> 11, t = row & 2047;
        if (col < 512) {
          const int c = col & 255;
          const int head = c >> 6, d = c & 63;
          const size_t idx = (((size_t)(b * NH + head)) * NT + t) * ND + d;
          const unsigned short hb = f2bf(v);
          if (col < 256) { Qhi[idx] = hb; Qlo[idx] = f2bf(v - bf2f(hb)); }
          else           { Khi[idx] = hb; Klo[idx] = f2bf(v - bf2f(hb)); }
        } else if (col < 516) {
          vubuf[((size_t)(b * NH + (col - 512))) * NT + t] = v;
        }
      }
}

// ---------------- attention v5: split-K x4, global_load_lds staging, no-max softmax ----
// Block 512 thr / 8 waves; wave = 32 q-rows; block = 256 q-rows x 512 k (8 tiles).
__global__ __launch_bounds__(512) void attn_kernel5(
    const unsigned short* __restrict__ qhi, const unsigned short* __restrict__ qlo,
    const unsigned short* __restrict__ khi, const unsigned short* __restrict__ klo,
    const float* __restrict__ vu, float2* __restrict__ part2)
{
  __shared__ __align__(16) char kbuf[2][16384];   // [buf][hi 8KB | lo 8KB], XOR-swizzled
  __shared__ float vu_s[512];
  const int tid = threadIdx.x;
  const int wave = tid >> 6, lane = tid & 63;
  const int lr = lane & 15, lg = lane >> 4;
  // XCD-aware: bid&7 -> XCD; each XCD covers 4 contiguous bh (K L2-resident)
  const int bid = blockIdx.x;                     // 0..1023
  const int g = bid >> 3;                         // 0..127
  const int bh = (bid & 7) * 4 + (g >> 5);
  const int rem = g & 31;
  const int qt = rem >> 2, kh = rem & 3;
  const size_t base = (size_t)bh * NT * ND;
  const int qrow0 = qt * 256 + wave * 32;
  const int krow0 = kh * 512;

  vu_s[tid] = vu[(size_t)bh * NT + krow0 + tid];

  // Q fragments in regs: [m-subtile][d-slice][hi/lo]
  bf16x8 qf[2][2][2];
  #pragma unroll
  for (int s = 0; s < 2; ++s)
    #pragma unroll
    for (int ds = 0; ds < 2; ++ds) {
      const size_t off = base + (size_t)(qrow0 + s * 16 + lr) * ND + ds * 32 + lg * 8;
      qf[s][ds][0] = *(const bf16x8*)(qhi + off);
      qf[s][ds][1] = *(const bf16x8*)(qlo + off);
    }

  // pre-swizzled global source offset (involution; LDS dest stays linear per lane)
  const int so = (tid * 16) ^ (((tid >> 3) & 7) << 4);
  int ro0[4], ro1[4];
  #pragma unroll
  for (int ns = 0; ns < 4; ++ns) {
    const int r = ns * 16 + lr;
    const int sw = (r & 7) << 4;
    const int ob = r * 128 + lg * 16;
    ro0[ns] = ob ^ sw;
    ro1[ns] = (ob + 64) ^ sw;
  }
  const char* srcH = (const char*)(khi + base + (size_t)krow0 * ND);
  const char* srcL = (const char*)(klo + base + (size_t)krow0 * ND);
  // prologue: stage tile 0 via async DMA
  gld16(srcH + so, &kbuf[0][wave * 1024]);
  gld16(srcL + so, &kbuf[0][8192 + wave * 1024]);

  float l[8], sv[8];
  #pragma unroll
  for (int i = 0; i < 8; ++i) { l[i] = 0.f; sv[i] = 0.f; }

  #pragma unroll 2
  for (int kt = 0; kt < 8; ++kt) {
    __syncthreads();                              // drains gload(kt): buf[kt&1] ready
    if (kt < 7) {                                 // issue next tile, in flight across compute
      char* nb = kbuf[(kt + 1) & 1];
      gld16(srcH + (kt + 1) * 8192 + so, nb + wave * 1024);
      gld16(srcL + (kt + 1) * 8192 + so, nb + 8192 + wave * 1024);
    }
    const char* kb = (const char*)kbuf[kt & 1];
    f32x4 acc[2][4];
    float vuv[4];
    #pragma unroll
    for (int ns = 0; ns < 4; ++ns) {
      const bf16x8 kh0 = *(const bf16x8*)(kb + ro0[ns]);
      const bf16x8 kh1 = *(const bf16x8*)(kb + ro1[ns]);
      const bf16x8 kl0 = *(const bf16x8*)(kb + 8192 + ro0[ns]);
      const bf16x8 kl1 = *(const bf16x8*)(kb + 8192 + ro1[ns]);
      vuv[ns] = vu_s[kt * 64 + ns * 16 + lr];
      #pragma unroll
      for (int s = 0; s < 2; ++s) {
        acc[s][ns] = (f32x4){0.f, 0.f, 0.f, 0.f};
        acc[s][ns] = __builtin_amdgcn_mfma_f32_16x16x32_bf16(qf[s][0][0], kh0, acc[s][ns], 0, 0, 0);
        acc[s][ns] = __builtin_amdgcn_mfma_f32_16x16x32_bf16(qf[s][0][0], kl0, acc[s][ns], 0, 0, 0);
        acc[s][ns] = __builtin_amdgcn_mfma_f32_16x16x32_bf16(qf[s][0][1], kh0, acc[s][ns], 0, 0, 0);
        acc[s][ns] = __builtin_amdgcn_mfma_f32_16x16x32_bf16(qf[s][1][0], kh1, acc[s][ns], 0, 0, 0);
        acc[s][ns] = __builtin_amdgcn_mfma_f32_16x16x32_bf16(qf[s][1][0], kl1, acc[s][ns], 0, 0, 0);
        acc[s][ns] = __builtin_amdgcn_mfma_f32_16x16x32_bf16(qf[s][1][1], kh1, acc[s][ns], 0, 0, 0);
      }
    }
    // no-max softmax accumulation (scores pre-scaled by 0.125 via q weights)
    #pragma unroll
    for (int s = 0; s < 2; ++s)
      #pragma unroll
      for (int reg = 0; reg < 4; ++reg) {
        const int ri = s * 4 + reg;
        #pragma unroll
        for (int ns = 0; ns < 4; ++ns) {
          const float e = __expf(acc[s][ns][reg]);
          l[ri] += e;
          sv[ri] = fmaf(e, vuv[ns], sv[ri]);
        }
      }
  }
  // reduce partial l/sv across the 16-lane column group
  #pragma unroll
  for (int ri = 0; ri < 8; ++ri) {
    #pragma unroll
    for (int off = 1; off < 16; off <<= 1) {
      l[ri]  += __shfl_xor(l[ri],  off, 16);
      sv[ri] += __shfl_xor(sv[ri], off, 16);
    }
  }
  if (lr == 0) {
    #pragma unroll
    for (int s = 0; s < 2; ++s)
      #pragma unroll
      for (int reg = 0; reg < 4; ++reg) {
        const int row = qrow0 + s * 16 + lg * 4 + reg;
        part2[(((size_t)bh * NT + row) << 2) + kh] = make_float2(l[s * 4 + reg], sv[s * 4 + reg]);
      }
  }
}

// ---------------- boundary: combine split-K x4, sigmoid, cumsum, pid, counts -----------
__global__ __launch_bounds__(256) void boundary_kernel(
    const float4* __restrict__ part4, const float* __restrict__ consts,
    int* __restrict__ pid, int* __restrict__ counts)
{
  const int b = blockIdx.x, tid = threadIdx.x;
  __shared__ float partial[256];
  __shared__ int cnt_s[8];
  const float c = consts[0];
  float v[8];
  float run = 0.f;
  #pragma unroll
  for (int i = 0; i < 8; ++i) {
    const int t = tid * 8 + i;
    float logit = c;
    #pragma unroll
    for (int hh = 0; hh < NH; ++hh) {
      const size_t p0 = ((size_t)(b * NH + hh) * NT + t) * 2;
      const float4 a = part4[p0];                 // {l0, sv0, l1, sv1}
      const float4 d = part4[p0 + 1];             // {l2, sv2, l3, sv3}
      logit += (a.y + a.w + d.y + d.w) / (a.x + a.z + d.x + d.z);
    }
    const float bs = 1.f / (1.f + expf(-logit));
    run += bs;
    v[i] = run;
  }
  float x = run;
  partial[tid] = x;
  __syncthreads();
  for (int off = 1; off < 256; off <<= 1) {
    const float y = (tid >= off) ? partial[tid - off] : 0.f;
    __syncthreads();
    x += y;
    partial[tid] = x;
    __syncthreads();
  }
  const float total = partial[255];
  if (tid < 8) cnt_s[tid] = 0;
  __syncthreads();
  const float denom = fmaxf(total, 1e-6f);
  const float excl = x - run;
  #pragma unroll
  for (int i = 0; i < 8; ++i) {
    const float norm = (excl + v[i]) / denom;
    int pp = (int)(norm * 8.f);
    pp = pp > 7 ? 7 : pp;
    pid[b * NT + tid * 8 + i] = pp;
    atomicAdd(&cnt_s[pp], 1);
  }
  __syncthreads();
  if (tid < 8) counts[b * 8 + tid] = cnt_s[tid];
}

// ---------------- pool hhi into patch sums (branchless 8-way select) -------------------
__global__ __launch_bounds__(256) void pool_kernel(
    const unsigned short* __restrict__ hhi, const int* __restrict__ pid,
    float* __restrict__ psum)
{
  const int b = blockIdx.x >> 4, chunk = blockIdx.x & 15;
  const int tid = threadIdx.x;
  __shared__ int pid_s[128];
  const int t0 = chunk * 128;
  if (tid < 128) pid_s[tid] = pid[b * NT + t0 + tid];
  __syncthreads();
  float acc[8] = {};
  for (int tok = 0; tok < 128; ++tok) {
    const float val = bf2f(hhi[((size_t)b * NT + t0 + tok) * NE + tid]);
    const int p = pid_s[tok];
    #pragma unroll
    for (int pp = 0; pp < 8; ++pp) acc[pp] += (p == pp) ? val : 0.f;
  }
  #pragma unroll
  for (int pp = 0; pp < 8; ++pp)
    atomicAdd(&psum[((size_t)b * NP + pp) * NE + tid], acc[pp]);
}

// ---------------- final: out = (psum/count) @ w_pr^T + b_pr ---------------------------
__global__ __launch_bounds__(256) void final_kernel(
    const float* __restrict__ psum, const int* __restrict__ counts,
    const float* __restrict__ w_pr, const float* __restrict__ b_pr, float* __restrict__ out)
{
  const int bp = blockIdx.x;
  const int tid = threadIdx.x;
  __shared__ float pe[NE];
  const float cnt = fmaxf((float)counts[bp], 1.f);
  pe[tid] = psum[(size_t)bp * NE + tid] / cnt;
  __syncthreads();
  float acc = 0.f;
  for (int e = 0; e < NE; ++e) acc = fmaf(pe[e], w_pr[(size_t)tid * NE + e], acc);
  out[(size_t)bp * NE + tid] = acc + b_pr[tid];
}

extern "C" void kernel_launch(void* const* d_in, const int* in_sizes, int n_in,
                              void* d_out, int out_size, void* d_ws, size_t ws_size,
                              hipStream_t stream) {
  (void)in_sizes; (void)n_in; (void)out_size; (void)ws_size;
  const float* x    = (const float*)d_in[0];
  const float* w_in = (const float*)d_in[1];
  const float* b_in = (const float*)d_in[2];
  const float* w_q  = (const float*)d_in[3];
  const float* b_q  = (const float*)d_in[4];
  const float* w_k  = (const float*)d_in[5];
  const float* b_k  = (const float*)d_in[6];
  const float* w_v  = (const float*)d_in[7];
  const float* b_v  = (const float*)d_in[8];
  const float* w_o  = (const float*)d_in[9];
  const float* b_o  = (const float*)d_in[10];
  const float* w_bd = (const float*)d_in[11];
  const float* b_bd = (const float*)d_in[12];
  const float* w_pr = (const float*)d_in[13];
  const float* b_pr = (const float*)d_in[14];
  float* out = (float*)d_out;

  const size_t M = (size_t)NB * NT;                       // 16384
  unsigned short* hhi = (unsigned short*)d_ws;            // M*NE u16 each
  unsigned short* hlo = hhi + M * NE;
  unsigned short* qhi = hlo + M * NE;
  unsigned short* qlo = qhi + M * NE;
  unsigned short* khi = qlo + M * NE;
  unsigned short* klo = khi + M * NE;
  unsigned short* wihi = klo + M * NE;                    // 65,536 each
  unsigned short* wilo = wihi + 65536;
  unsigned short* wqkvhi = wilo + 65536;                  // 147,456 each (576x256)
  unsigned short* wqkvlo = wqkvhi + 147456;
  float* bqk    = (float*)(wqkvlo + 147456);              // 576
  float* vubuf  = bqk + 576;                              // 65,536 [B,H,T]
  float* part   = vubuf + 65536;                          // 524,288 [bh][t][kh][{l,sv}]
  float* consts = part + 524288;                          // 8
  float* psum   = consts + 8;                             // 16,384
  int*   pid    = (int*)(psum + 16384);                   // 16,384
  int*   counts = pid + 16384;                            // 64

  setup_kernel<<<578, 256, 0, stream>>>(w_in, w_q, w_k, b_q, b_k, w_o, b_o,
      w_bd, b_bd, w_v, b_v, wihi, wilo, wqkvhi, wqkvlo, bqk, consts, psum);
  hgemm_kernel<<<dim3(4, 128), 256, 0, stream>>>(x, wihi, wilo, b_in, hhi, hlo);
  qkvgemm_kernel<<<dim3(9, 128), 256, 0, stream>>>(hhi, hlo, wqkvhi, wqkvlo, bqk,
      qhi, qlo, khi, klo, vubuf);
  attn_kernel5<<<1024, 512, 0, stream>>>(qhi, qlo, khi, klo, vubuf, (float2*)part);
  boundary_kernel<<<8, 256, 0, stream>>>((const float4*)part, consts, pid, counts);
  pool_kernel<<<128, 256, 0, stream>>>(hhi, pid, psum);
  final_kernel<<<64, 256, 0, stream>>>(psum, counts, w_pr, b_pr, out);
}

// Round 7
// 157.868 us; speedup vs baseline: 1.3497x; 1.3497x over previous
//
#include <hip/hip_runtime.h>
#include <cstddef>

#define NB 8
#define NT 2048
#define NE 256
#define NH 4
#define ND 64
#define NP 8

typedef short bf16x8 __attribute__((ext_vector_type(8)));
typedef float f32x4 __attribute__((ext_vector_type(4)));

__device__ __forceinline__ unsigned short f2bf(float f) {
  unsigned u = __builtin_bit_cast(unsigned, f);
  u += 0x7fffu + ((u >> 16) & 1u);          // RNE
  return (unsigned short)(u >> 16);
}
__device__ __forceinline__ float bf2f(unsigned short h) {
  unsigned u = ((unsigned)h) << 16;
  return __builtin_bit_cast(float, u);
}
// packed hi/lo split of a float pair (integer-only)
__device__ __forceinline__ void split2(float a, float b, unsigned& hi, unsigned& lo) {
  const unsigned short ha = f2bf(a), hb = f2bf(b);
  hi = (unsigned)ha | ((unsigned)hb << 16);
  const unsigned short la = f2bf(a - bf2f(ha));
  const unsigned short lb = f2bf(b - bf2f(hb));
  lo = (unsigned)la | ((unsigned)lb << 16);
}
__device__ __forceinline__ void gld16(const void* g, void* l) {
  __builtin_amdgcn_global_load_lds((const __attribute__((address_space(1))) unsigned*)g,
                                   (__attribute__((address_space(3))) unsigned*)l, 16, 0, 0);
}

// ---------------- setup: wqk split(+q prescale), w_in split, prep(uv->wqkv rows), zero --
// grid 578: [0,512) wqk, [512,576) w_in, 576 prep, 577 psum-zero
__global__ __launch_bounds__(256) void setup_kernel(
    const float* __restrict__ w_in, const float* __restrict__ w_q,
    const float* __restrict__ w_k, const float* __restrict__ b_q,
    const float* __restrict__ b_k, const float* __restrict__ w_o,
    const float* __restrict__ b_o, const float* __restrict__ w_bd,
    const float* __restrict__ b_bd, const float* __restrict__ w_v,
    const float* __restrict__ b_v,
    unsigned short* __restrict__ wihi, unsigned short* __restrict__ wilo,
    unsigned short* __restrict__ wqkvhi, unsigned short* __restrict__ wqkvlo,
    float* __restrict__ bqk, float* __restrict__ consts, float* __restrict__ psum)
{
  __shared__ float wbd_s[NE];
  __shared__ float u_s[NE];
  const int b = blockIdx.x, tid = threadIdx.x;
  if (b < 512) {
    const int i = b * 256 + tid;                         // [0,131072)
    const float v = (i < 65536) ? w_q[i] * 0.125f : w_k[i - 65536];
    const unsigned short h = f2bf(v);
    wqkvhi[i] = h;
    wqkvlo[i] = f2bf(v - bf2f(h));
    if (i < 512) bqk[i] = (i < 256) ? b_q[i] * 0.125f : b_k[i - 256];
  } else if (b < 576) {
    const int i = (b - 512) * 256 + tid;                 // float4 idx [0,16384)
    const float4 v = *(const float4*)(w_in + (size_t)i * 4);
    const float vv[4] = {v.x, v.y, v.z, v.w};
    unsigned short h4[4], l4[4];
    #pragma unroll
    for (int j = 0; j < 4; ++j) {
      h4[j] = f2bf(vv[j]);
      l4[j] = f2bf(vv[j] - bf2f(h4[j]));
    }
    *(ushort2*)(wihi + (size_t)i * 4)     = make_ushort2(h4[0], h4[1]);
    *(ushort2*)(wihi + (size_t)i * 4 + 2) = make_ushort2(h4[2], h4[3]);
    *(ushort2*)(wilo + (size_t)i * 4)     = make_ushort2(l4[0], l4[1]);
    *(ushort2*)(wilo + (size_t)i * 4 + 2) = make_ushort2(l4[2], l4[3]);
  } else if (b == 576) {
    wbd_s[tid] = w_bd[tid];
    __syncthreads();
    float a = 0.f;
    for (int j = 0; j < NE; ++j) a = fmaf(wbd_s[j], w_o[j * NE + tid], a);
    u_s[tid] = a;
    __syncthreads();
    #pragma unroll
    for (int hh = 0; hh < NH; ++hh) {
      float a2 = 0.f;
      for (int d = 0; d < ND; ++d)
        a2 = fmaf(u_s[hh * ND + d], w_v[(size_t)(hh * ND + d) * NE + tid], a2);
      const unsigned short hb = f2bf(a2);
      wqkvhi[(512 + hh) * 256 + tid] = hb;
      wqkvlo[(512 + hh) * 256 + tid] = f2bf(a2 - bf2f(hb));
    }
    for (int i = tid; i < 60 * 256; i += 256) {          // zero-pad rows 516..575
      wqkvhi[516 * 256 + i] = 0;
      wqkvlo[516 * 256 + i] = 0;
    }
    if (tid == 0) {
      float cc = 0.f;
      for (int j = 0; j < NE; ++j) cc = fmaf(wbd_s[j], b_o[j], cc);
      consts[0] = cc + b_bd[0];
    }
    if (tid < 4) {
      float cv = 0.f;
      for (int d = 0; d < ND; ++d) cv = fmaf(u_s[tid * ND + d], b_v[tid * ND + d], cv);
      bqk[512 + tid] = cv;
    } else if (tid < 64) {
      bqk[512 + tid] = 0.f;
    }
  } else {
    for (int i = tid; i < NB * NP * NE; i += 256) psum[i] = 0.f;
  }
}

// ---------------- hgemm v2: LDS-staged, dbuf, gld16. h = x @ w_in^T + b_in -------------
// BM=128 BN=64 BK=32; 256 thr = 4 waves (2m x 2n); grid 512 XCD-swizzled.
// LDS/buf: x f32 [128][32] @0 (16K), Whi [64][32] @16K (4K), Wlo @20K (4K). dbuf 48K.
__global__ __launch_bounds__(256) void hgemm_kernel(
    const float* __restrict__ x,
    const unsigned short* __restrict__ wihi, const unsigned short* __restrict__ wilo,
    const float* __restrict__ b_in,
    unsigned short* __restrict__ hhi, unsigned short* __restrict__ hlo)
{
  __shared__ __align__(16) char sm[2][24576];
  const int tid = threadIdx.x;
  const int wave = tid >> 6, lane = tid & 63;
  const int lr = lane & 15, lg = lane >> 4;
  const int wm = wave >> 1, wn = wave & 1;
  // XCD decode: 512 blocks; xcd gets 16 contiguous m-tiles (x-panel 2MB, L2-fit)
  const int bid = blockIdx.x;
  const int idx = bid >> 3;
  const int m0 = ((bid & 7) * 16 + (idx >> 2)) * 128;
  const int n0 = (idx & 3) * 64;

  // staging sources (pre-swizzled global, linear LDS dest)
  const float* aSrc[4];
  #pragma unroll
  for (int c = 0; c < 4; ++c) {
    const int L = c * 4096 + tid * 16;
    const int row = L >> 7, w = (L >> 4) & 7;
    aSrc[c] = x + (size_t)(m0 + row) * 256 + (w ^ (row & 7)) * 4;
  }
  const unsigned short* wSrc[2];
  #pragma unroll
  for (int c = 0; c < 2; ++c) {
    const int L = c * 4096 + tid * 16;
    const int half = (L >> 12) & 1;
    const int Lh = L & 4095;
    const int col = Lh >> 6, w = (Lh >> 4) & 3;
    wSrc[c] = (half ? wilo : wihi) + (size_t)(n0 + col) * 256 + (w ^ ((col >> 1) & 3)) * 8;
  }
  // frag read offsets (same involutions)
  int aoff[4][2], woff[2];
  #pragma unroll
  for (int s = 0; s < 4; ++s) {
    const int row = wm * 64 + s * 16 + lr;
    const int b0 = row * 128 + lg * 32;
    const int f = (row & 7) << 4;
    aoff[s][0] = b0 ^ f;
    aoff[s][1] = (b0 + 16) ^ f;
  }
  #pragma unroll
  for (int ns = 0; ns < 2; ++ns) {
    const int col = wn * 32 + ns * 16 + lr;
    woff[ns] = (col * 64 + lg * 16) ^ (((col >> 1) & 3) << 4);
  }

  f32x4 acc[4][2];
  #pragma unroll
  for (int s = 0; s < 4; ++s)
    #pragma unroll
    for (int ns = 0; ns < 2; ++ns) acc[s][ns] = (f32x4){0.f, 0.f, 0.f, 0.f};

  // prologue: stage k-step 0
  {
    char* lb = sm[0];
    #pragma unroll
    for (int c = 0; c < 4; ++c) gld16(aSrc[c], lb + c * 4096 + wave * 1024);
    #pragma unroll
    for (int c = 0; c < 2; ++c) gld16(wSrc[c], lb + 16384 + c * 4096 + wave * 1024);
  }

  for (int kt = 0; kt < 8; ++kt) {
    __syncthreads();                            // drains gld16 for buf[kt&1]
    if (kt < 7) {
      char* nb = sm[(kt + 1) & 1];
      #pragma unroll
      for (int c = 0; c < 4; ++c) gld16(aSrc[c] + (kt + 1) * 32, nb + c * 4096 + wave * 1024);
      #pragma unroll
      for (int c = 0; c < 2; ++c) gld16(wSrc[c] + (kt + 1) * 32, nb + 16384 + c * 4096 + wave * 1024);
    }
    const char* lb = sm[kt & 1];
    bf16x8 ah[4], al[4], wh[2], wl[2];
    #pragma unroll
    for (int s = 0; s < 4; ++s) {
      const f32x4 p0 = *(const f32x4*)(lb + aoff[s][0]);
      const f32x4 p1 = *(const f32x4*)(lb + aoff[s][1]);
      unsigned h0, h1, h2, h3, l0, l1, l2, l3;
      split2(p0[0], p0[1], h0, l0);
      split2(p0[2], p0[3], h1, l1);
      split2(p1[0], p1[1], h2, l2);
      split2(p1[2], p1[3], h3, l3);
      const uint4 hu = make_uint4(h0, h1, h2, h3);
      const uint4 lu = make_uint4(l0, l1, l2, l3);
      ah[s] = __builtin_bit_cast(bf16x8, hu);
      al[s] = __builtin_bit_cast(bf16x8, lu);
    }
    #pragma unroll
    for (int ns = 0; ns < 2; ++ns) {
      wh[ns] = *(const bf16x8*)(lb + 16384 + woff[ns]);
      wl[ns] = *(const bf16x8*)(lb + 20480 + woff[ns]);
    }
    #pragma unroll
    for (int s = 0; s < 4; ++s)
      #pragma unroll
      for (int ns = 0; ns < 2; ++ns) {
        acc[s][ns] = __builtin_amdgcn_mfma_f32_16x16x32_bf16(ah[s], wh[ns], acc[s][ns], 0, 0, 0);
        acc[s][ns] = __builtin_amdgcn_mfma_f32_16x16x32_bf16(ah[s], wl[ns], acc[s][ns], 0, 0, 0);
        acc[s][ns] = __builtin_amdgcn_mfma_f32_16x16x32_bf16(al[s], wh[ns], acc[s][ns], 0, 0, 0);
      }
  }
  #pragma unroll
  for (int s = 0; s < 4; ++s)
    #pragma unroll
    for (int ns = 0; ns < 2; ++ns)
      #pragma unroll
      for (int reg = 0; reg < 4; ++reg) {
        const int row = m0 + wm * 64 + s * 16 + lg * 4 + reg;
        const int col = n0 + wn * 32 + ns * 16 + lr;
        const float v = acc[s][ns][reg] + b_in[col];
        const size_t i2 = (size_t)row * 256 + col;
        const unsigned short hb = f2bf(v);
        hhi[i2] = hb;
        hlo[i2] = f2bf(v - bf2f(hb));
      }
}

// ---------------- qkv-gemm v2: LDS-staged dbuf. [q*0.125|k|vu] = h @ wqkv^T + bqk ------
// BM=128 BN=64 BK=32; grid 1152 XCD-swizzled. LDS/buf: Ahi@0 Alo@8K Whi@16K Wlo@20K.
__global__ __launch_bounds__(256) void qkvgemm_kernel(
    const unsigned short* __restrict__ Ahi, const unsigned short* __restrict__ Alo,
    const unsigned short* __restrict__ Whi, const unsigned short* __restrict__ Wlo,
    const float* __restrict__ bias,
    unsigned short* __restrict__ Qhi, unsigned short* __restrict__ Qlo,
    unsigned short* __restrict__ Khi, unsigned short* __restrict__ Klo,
    float* __restrict__ vubuf)
{
  __shared__ __align__(16) char sm[2][24576];
  const int tid = threadIdx.x;
  const int wave = tid >> 6, lane = tid & 63;
  const int lr = lane & 15, lg = lane >> 4;
  const int wm = wave >> 1, wn = wave & 1;
  // XCD decode: 1152 blocks = 8 xcd * (16 m-tiles * 9 n-tiles); A-band 2MB/XCD L2-fit
  const int bid = blockIdx.x;
  const int idx = bid >> 3;                     // 0..143
  const int m0 = ((bid & 7) * 16 + idx / 9) * 128;
  const int n0 = (idx % 9) * 64;

  const unsigned short* aSrc[4];
  #pragma unroll
  for (int c = 0; c < 4; ++c) {
    const int L = c * 4096 + tid * 16;
    const int half = L >> 13;
    const int Lh = L & 8191;
    const int row = Lh >> 6, w = (Lh >> 4) & 3;
    aSrc[c] = (half ? Alo : Ahi) + (size_t)(m0 + row) * 256 + (w ^ ((row >> 1) & 3)) * 8;
  }
  const unsigned short* wSrc[2];
  #pragma unroll
  for (int c = 0; c < 2; ++c) {
    const int L = c * 4096 + tid * 16;
    const int half = (L >> 12) & 1;
    const int Lh = L & 4095;
    const int col = Lh >> 6, w = (Lh >> 4) & 3;
    wSrc[c] = (half ? Wlo : Whi) + (size_t)(n0 + col) * 256 + (w ^ ((col >> 1) & 3)) * 8;
  }
  int aoff[4], woff[2];
  #pragma unroll
  for (int s = 0; s < 4; ++s) {
    const int row = wm * 64 + s * 16 + lr;
    aoff[s] = (row * 64 + lg * 16) ^ (((row >> 1) & 3) << 4);
  }
  #pragma unroll
  for (int ns = 0; ns < 2; ++ns) {
    const int col = wn * 32 + ns * 16 + lr;
    woff[ns] = (col * 64 + lg * 16) ^ (((col >> 1) & 3) << 4);
  }

  f32x4 acc[4][2];
  #pragma unroll
  for (int s = 0; s < 4; ++s)
    #pragma unroll
    for (int ns = 0; ns < 2; ++ns) acc[s][ns] = (f32x4){0.f, 0.f, 0.f, 0.f};

  {
    char* lb = sm[0];
    #pragma unroll
    for (int c = 0; c < 4; ++c) gld16(aSrc[c], lb + c * 4096 + wave * 1024);
    #pragma unroll
    for (int c = 0; c < 2; ++c) gld16(wSrc[c], lb + 16384 + c * 4096 + wave * 1024);
  }

  for (int kt = 0; kt < 8; ++kt) {
    __syncthreads();
    if (kt < 7) {
      char* nb = sm[(kt + 1) & 1];
      #pragma unroll
      for (int c = 0; c < 4; ++c) gld16(aSrc[c] + (kt + 1) * 32, nb + c * 4096 + wave * 1024);
      #pragma unroll
      for (int c = 0; c < 2; ++c) gld16(wSrc[c] + (kt + 1) * 32, nb + 16384 + c * 4096 + wave * 1024);
    }
    const char* lb = sm[kt & 1];
    bf16x8 ah[4], al[4], wh[2], wl[2];
    #pragma unroll
    for (int s = 0; s < 4; ++s) {
      ah[s] = *(const bf16x8*)(lb + aoff[s]);
      al[s] = *(const bf16x8*)(lb + 8192 + aoff[s]);
    }
    #pragma unroll
    for (int ns = 0; ns < 2; ++ns) {
      wh[ns] = *(const bf16x8*)(lb + 16384 + woff[ns]);
      wl[ns] = *(const bf16x8*)(lb + 20480 + woff[ns]);
    }
    #pragma unroll
    for (int s = 0; s < 4; ++s)
      #pragma unroll
      for (int ns = 0; ns < 2; ++ns) {
        acc[s][ns] = __builtin_amdgcn_mfma_f32_16x16x32_bf16(ah[s], wh[ns], acc[s][ns], 0, 0, 0);
        acc[s][ns] = __builtin_amdgcn_mfma_f32_16x16x32_bf16(ah[s], wl[ns], acc[s][ns], 0, 0, 0);
        acc[s][ns] = __builtin_amdgcn_mfma_f32_16x16x32_bf16(al[s], wh[ns], acc[s][ns], 0, 0, 0);
      }
  }
  #pragma unroll
  for (int s = 0; s < 4; ++s)
    #pragma unroll
    for (int ns = 0; ns < 2; ++ns)
      #pragma unroll
      for (int reg = 0; reg < 4; ++reg) {
        const int row = m0 + wm * 64 + s * 16 + lg * 4 + reg;
        const int col = n0 + wn * 32 + ns * 16 + lr;
        const float v = acc[s][ns][reg] + bias[col];
        const int b = row >> 11, t = row & 2047;
        if (col < 512) {
          const int c = col & 255;
          const int head = c >> 6, d = c & 63;
          const size_t i2 = (((size_t)(b * NH + head)) * NT + t) * ND + d;
          const unsigned short hb = f2bf(v);
          if (col < 256) { Qhi[i2] = hb; Qlo[i2] = f2bf(v - bf2f(hb)); }
          else           { Khi[i2] = hb; Klo[i2] = f2bf(v - bf2f(hb)); }
        } else if (col < 516) {
          vubuf[((size_t)(b * NH + (col - 512))) * NT + t] = v;
        }
      }
}

// ---------------- attention v5: split-K x4, global_load_lds staging, no-max softmax ----
__global__ __launch_bounds__(512) void attn_kernel5(
    const unsigned short* __restrict__ qhi, const unsigned short* __restrict__ qlo,
    const unsigned short* __restrict__ khi, const unsigned short* __restrict__ klo,
    const float* __restrict__ vu, float2* __restrict__ part2)
{
  __shared__ __align__(16) char kbuf[2][16384];   // [buf][hi 8KB | lo 8KB], XOR-swizzled
  __shared__ float vu_s[512];
  const int tid = threadIdx.x;
  const int wave = tid >> 6, lane = tid & 63;
  const int lr = lane & 15, lg = lane >> 4;
  const int bid = blockIdx.x;                     // 0..1023
  const int g = bid >> 3;                         // 0..127
  const int bh = (bid & 7) * 4 + (g >> 5);
  const int rem = g & 31;
  const int qt = rem >> 2, kh = rem & 3;
  const size_t base = (size_t)bh * NT * ND;
  const int qrow0 = qt * 256 + wave * 32;
  const int krow0 = kh * 512;

  vu_s[tid] = vu[(size_t)bh * NT + krow0 + tid];

  bf16x8 qf[2][2][2];
  #pragma unroll
  for (int s = 0; s < 2; ++s)
    #pragma unroll
    for (int ds = 0; ds < 2; ++ds) {
      const size_t off = base + (size_t)(qrow0 + s * 16 + lr) * ND + ds * 32 + lg * 8;
      qf[s][ds][0] = *(const bf16x8*)(qhi + off);
      qf[s][ds][1] = *(const bf16x8*)(qlo + off);
    }

  const int so = (tid * 16) ^ (((tid >> 3) & 7) << 4);
  int ro0[4], ro1[4];
  #pragma unroll
  for (int ns = 0; ns < 4; ++ns) {
    const int r = ns * 16 + lr;
    const int sw = (r & 7) << 4;
    const int ob = r * 128 + lg * 16;
    ro0[ns] = ob ^ sw;
    ro1[ns] = (ob + 64) ^ sw;
  }
  const char* srcH = (const char*)(khi + base + (size_t)krow0 * ND);
  const char* srcL = (const char*)(klo + base + (size_t)krow0 * ND);
  gld16(srcH + so, &kbuf[0][wave * 1024]);
  gld16(srcL + so, &kbuf[0][8192 + wave * 1024]);

  float l[8], sv[8];
  #pragma unroll
  for (int i = 0; i < 8; ++i) { l[i] = 0.f; sv[i] = 0.f; }

  #pragma unroll 2
  for (int kt = 0; kt < 8; ++kt) {
    __syncthreads();
    if (kt < 7) {
      char* nb = kbuf[(kt + 1) & 1];
      gld16(srcH + (kt + 1) * 8192 + so, nb + wave * 1024);
      gld16(srcL + (kt + 1) * 8192 + so, nb + 8192 + wave * 1024);
    }
    const char* kb = (const char*)kbuf[kt & 1];
    f32x4 acc[2][4];
    float vuv[4];
    #pragma unroll
    for (int ns = 0; ns < 4; ++ns) {
      const bf16x8 kh0 = *(const bf16x8*)(kb + ro0[ns]);
      const bf16x8 kh1 = *(const bf16x8*)(kb + ro1[ns]);
      const bf16x8 kl0 = *(const bf16x8*)(kb + 8192 + ro0[ns]);
      const bf16x8 kl1 = *(const bf16x8*)(kb + 8192 + ro1[ns]);
      vuv[ns] = vu_s[kt * 64 + ns * 16 + lr];
      #pragma unroll
      for (int s = 0; s < 2; ++s) {
        acc[s][ns] = (f32x4){0.f, 0.f, 0.f, 0.f};
        acc[s][ns] = __builtin_amdgcn_mfma_f32_16x16x32_bf16(qf[s][0][0], kh0, acc[s][ns], 0, 0, 0);
        acc[s][ns] = __builtin_amdgcn_mfma_f32_16x16x32_bf16(qf[s][0][0], kl0, acc[s][ns], 0, 0, 0);
        acc[s][ns] = __builtin_amdgcn_mfma_f32_16x16x32_bf16(qf[s][0][1], kh0, acc[s][ns], 0, 0, 0);
        acc[s][ns] = __builtin_amdgcn_mfma_f32_16x16x32_bf16(qf[s][1][0], kh1, acc[s][ns], 0, 0, 0);
        acc[s][ns] = __builtin_amdgcn_mfma_f32_16x16x32_bf16(qf[s][1][0], kl1, acc[s][ns], 0, 0, 0);
        acc[s][ns] = __builtin_amdgcn_mfma_f32_16x16x32_bf16(qf[s][1][1], kh1, acc[s][ns], 0, 0, 0);
      }
    }
    #pragma unroll
    for (int s = 0; s < 2; ++s)
      #pragma unroll
      for (int reg = 0; reg < 4; ++reg) {
        const int ri = s * 4 + reg;
        #pragma unroll
        for (int ns = 0; ns < 4; ++ns) {
          const float e = __expf(acc[s][ns][reg]);
          l[ri] += e;
          sv[ri] = fmaf(e, vuv[ns], sv[ri]);
        }
      }
  }
  #pragma unroll
  for (int ri = 0; ri < 8; ++ri) {
    #pragma unroll
    for (int off = 1; off < 16; off <<= 1) {
      l[ri]  += __shfl_xor(l[ri],  off, 16);
      sv[ri] += __shfl_xor(sv[ri], off, 16);
    }
  }
  if (lr == 0) {
    #pragma unroll
    for (int s = 0; s < 2; ++s)
      #pragma unroll
      for (int reg = 0; reg < 4; ++reg) {
        const int row = qrow0 + s * 16 + lg * 4 + reg;
        part2[(((size_t)bh * NT + row) << 2) + kh] = make_float2(l[s * 4 + reg], sv[s * 4 + reg]);
      }
  }
}

// ---------------- boundary: combine split-K x4, sigmoid, cumsum, pid, counts -----------
__global__ __launch_bounds__(256) void boundary_kernel(
    const float4* __restrict__ part4, const float* __restrict__ consts,
    int* __restrict__ pid, int* __restrict__ counts)
{
  const int b = blockIdx.x, tid = threadIdx.x;
  __shared__ float partial[256];
  __shared__ int cnt_s[8];
  const float c = consts[0];
  float v[8];
  float run = 0.f;
  #pragma unroll
  for (int i = 0; i < 8; ++i) {
    const int t = tid * 8 + i;
    float logit = c;
    #pragma unroll
    for (int hh = 0; hh < NH; ++hh) {
      const size_t p0 = ((size_t)(b * NH + hh) * NT + t) * 2;
      const float4 a = part4[p0];
      const float4 d = part4[p0 + 1];
      logit += (a.y + a.w + d.y + d.w) / (a.x + a.z + d.x + d.z);
    }
    const float bs = 1.f / (1.f + expf(-logit));
    run += bs;
    v[i] = run;
  }
  float x = run;
  partial[tid] = x;
  __syncthreads();
  for (int off = 1; off < 256; off <<= 1) {
    const float y = (tid >= off) ? partial[tid - off] : 0.f;
    __syncthreads();
    x += y;
    partial[tid] = x;
    __syncthreads();
  }
  const float total = partial[255];
  if (tid < 8) cnt_s[tid] = 0;
  __syncthreads();
  const float denom = fmaxf(total, 1e-6f);
  const float excl = x - run;
  #pragma unroll
  for (int i = 0; i < 8; ++i) {
    const float norm = (excl + v[i]) / denom;
    int pp = (int)(norm * 8.f);
    pp = pp > 7 ? 7 : pp;
    pid[b * NT + tid * 8 + i] = pp;
    atomicAdd(&cnt_s[pp], 1);
  }
  __syncthreads();
  if (tid < 8) counts[b * 8 + tid] = cnt_s[tid];
}

// ---------------- pool hhi into patch sums (branchless 8-way select) -------------------
__global__ __launch_bounds__(256) void pool_kernel(
    const unsigned short* __restrict__ hhi, const int* __restrict__ pid,
    float* __restrict__ psum)
{
  const int b = blockIdx.x >> 4, chunk = blockIdx.x & 15;
  const int tid = threadIdx.x;
  __shared__ int pid_s[128];
  const int t0 = chunk * 128;
  if (tid < 128) pid_s[tid] = pid[b * NT + t0 + tid];
  __syncthreads();
  float acc[8] = {};
  for (int tok = 0; tok < 128; ++tok) {
    const float val = bf2f(hhi[((size_t)b * NT + t0 + tok) * NE + tid]);
    const int p = pid_s[tok];
    #pragma unroll
    for (int pp = 0; pp < 8; ++pp) acc[pp] += (p == pp) ? val : 0.f;
  }
  #pragma unroll
  for (int pp = 0; pp < 8; ++pp)
    atomicAdd(&psum[((size_t)b * NP + pp) * NE + tid], acc[pp]);
}

// ---------------- final: out = (psum/count) @ w_pr^T + b_pr ---------------------------
__global__ __launch_bounds__(256) void final_kernel(
    const float* __restrict__ psum, const int* __restrict__ counts,
    const float* __restrict__ w_pr, const float* __restrict__ b_pr, float* __restrict__ out)
{
  const int bp = blockIdx.x;
  const int tid = threadIdx.x;
  __shared__ float pe[NE];
  const float cnt = fmaxf((float)counts[bp], 1.f);
  pe[tid] = psum[(size_t)bp * NE + tid] / cnt;
  __syncthreads();
  float acc = 0.f;
  for (int e = 0; e < NE; ++e) acc = fmaf(pe[e], w_pr[(size_t)tid * NE + e], acc);
  out[(size_t)bp * NE + tid] = acc + b_pr[tid];
}

extern "C" void kernel_launch(void* const* d_in, const int* in_sizes, int n_in,
                              void* d_out, int out_size, void* d_ws, size_t ws_size,
                              hipStream_t stream) {
  (void)in_sizes; (void)n_in; (void)out_size; (void)ws_size;
  const float* x    = (const float*)d_in[0];
  const float* w_in = (const float*)d_in[1];
  const float* b_in = (const float*)d_in[2];
  const float* w_q  = (const float*)d_in[3];
  const float* b_q  = (const float*)d_in[4];
  const float* w_k  = (const float*)d_in[5];
  const float* b_k  = (const float*)d_in[6];
  const float* w_v  = (const float*)d_in[7];
  const float* b_v  = (const float*)d_in[8];
  const float* w_o  = (const float*)d_in[9];
  const float* b_o  = (const float*)d_in[10];
  const float* w_bd = (const float*)d_in[11];
  const float* b_bd = (const float*)d_in[12];
  const float* w_pr = (const float*)d_in[13];
  const float* b_pr = (const float*)d_in[14];
  float* out = (float*)d_out;

  const size_t M = (size_t)NB * NT;                       // 16384
  unsigned short* hhi = (unsigned short*)d_ws;            // M*NE u16 each
  unsigned short* hlo = hhi + M * NE;
  unsigned short* qhi = hlo + M * NE;
  unsigned short* qlo = qhi + M * NE;
  unsigned short* khi = qlo + M * NE;
  unsigned short* klo = khi + M * NE;
  unsigned short* wihi = klo + M * NE;                    // 65,536 each
  unsigned short* wilo = wihi + 65536;
  unsigned short* wqkvhi = wilo + 65536;                  // 147,456 each (576x256)
  unsigned short* wqkvlo = wqkvhi + 147456;
  float* bqk    = (float*)(wqkvlo + 147456);              // 576
  float* vubuf  = bqk + 576;                              // 65,536 [B,H,T]
  float* part   = vubuf + 65536;                          // 524,288 [bh][t][kh][{l,sv}]
  float* consts = part + 524288;                          // 8
  float* psum   = consts + 8;                             // 16,384
  int*   pid    = (int*)(psum + 16384);                   // 16,384
  int*   counts = pid + 16384;                            // 64

  setup_kernel<<<578, 256, 0, stream>>>(w_in, w_q, w_k, b_q, b_k, w_o, b_o,
      w_bd, b_bd, w_v, b_v, wihi, wilo, wqkvhi, wqkvlo, bqk, consts, psum);
  hgemm_kernel<<<512, 256, 0, stream>>>(x, wihi, wilo, b_in, hhi, hlo);
  qkvgemm_kernel<<<1152, 256, 0, stream>>>(hhi, hlo, wqkvhi, wqkvlo, bqk,
      qhi, qlo, khi, klo, vubuf);
  attn_kernel5<<<1024, 512, 0, stream>>>(qhi, qlo, khi, klo, vubuf, (float2*)part);
  boundary_kernel<<<8, 256, 0, stream>>>((const float4*)part, consts, pid, counts);
  pool_kernel<<<128, 256, 0, stream>>>(hhi, pid, psum);
  final_kernel<<<64, 256, 0, stream>>>(psum, counts, w_pr, b_pr, out);
}